// Round 2
// baseline (285.400 us; speedup 1.0000x reference)
//
#include <hip/hip_runtime.h>

// Problem constants
#define BB 4
#define LLL 256
#define LPP 256
#define DDIM 256
#define HH 128

typedef _Float16 f16;
typedef f16 f16x8 __attribute__((ext_vector_type(8)));
typedef float floatx4 __attribute__((ext_vector_type(4)));

__device__ __forceinline__ float gelu_f(float x) {
    // x * sigmoid(1.702x): |err| vs erf-GELU < ~0.02, tolerance is 0.4 absolute.
    return x / (1.f + __expf(-1.702f * x));
}
__device__ __forceinline__ float sigmoid_f(float x) {
    return 1.f / (1.f + __expf(-x));
}
__device__ __forceinline__ f16x8 habs8(f16x8 v) {
    uint4 u = __builtin_bit_cast(uint4, v);
    u.x &= 0x7fff7fffu; u.y &= 0x7fff7fffu; u.z &= 0x7fff7fffu; u.w &= 0x7fff7fffu;
    return __builtin_bit_cast(f16x8, u);
}

// ---------------------------------------------------------------------------
// Kernel 0: convert W1c|W1d (cols 512..1023 of W1) and W2 to f16 in ws
// ---------------------------------------------------------------------------
__global__ void cvt_w(const float* __restrict__ W1, const float* __restrict__ W2,
                      f16* __restrict__ w1cd, f16* __restrict__ w2b) {
    int idx = blockIdx.x * 256 + threadIdx.x;
    if (idx < 128 * 512) {
        int h = idx >> 9, c = idx & 511;
        w1cd[idx] = (f16)W1[h * 1024 + 512 + c];
    } else {
        int j = idx - 128 * 512;
        if (j < 128 * 128) w2b[j] = (f16)W2[j];
    }
}

// ---------------------------------------------------------------------------
// Kernel 1: projections. proj[m][e], m in [0,1024): l rows, [1024,2048): p rows
// proj = tok @ W^T + bias  (f16 out). Block tile 64x64, 4 waves, 16x16x32 MFMA
// ---------------------------------------------------------------------------
__global__ __launch_bounds__(256) void prep_proj(
    const float* __restrict__ l_tok, const float* __restrict__ p_tok,
    const float* __restrict__ Wl, const float* __restrict__ Wp,
    const float* __restrict__ bl, const float* __restrict__ bp,
    f16* __restrict__ proj) {
    __shared__ __align__(16) char sm[2 * 64 * 80];
    f16* As = (f16*)sm;             // 64 x 40 (32 + 8 pad)
    f16* Bs = (f16*)(sm + 64 * 80);
    int tid = threadIdx.x;
    int m0 = blockIdx.x * 64, n0 = blockIdx.y * 64;
    bool isP = (m0 >= 1024);
    const float* Asrc = isP ? (p_tok + (size_t)(m0 - 1024) * DDIM) : (l_tok + (size_t)m0 * DDIM);
    const float* Wsrc = isP ? Wp : Wl;
    const float* bias = isP ? bp : bl;
    int row = tid >> 2, seg = tid & 3;
    int w = tid >> 6, lane = tid & 63;
    int m16 = lane & 15, quad = lane >> 4;
    int wm = w & 1, wn = w >> 1;
    floatx4 acc[2][2];
#pragma unroll
    for (int a = 0; a < 2; ++a)
#pragma unroll
        for (int c = 0; c < 2; ++c) acc[a][c] = (floatx4)0.f;
    for (int k0 = 0; k0 < DDIM; k0 += 32) {
        float4 f0 = *(const float4*)(Asrc + row * DDIM + k0 + seg * 8);
        float4 f1 = *(const float4*)(Asrc + row * DDIM + k0 + seg * 8 + 4);
        f16x8 av;
        av[0] = (f16)f0.x; av[1] = (f16)f0.y; av[2] = (f16)f0.z; av[3] = (f16)f0.w;
        av[4] = (f16)f1.x; av[5] = (f16)f1.y; av[6] = (f16)f1.z; av[7] = (f16)f1.w;
        *(f16x8*)(As + row * 40 + seg * 8) = av;
        float4 g0 = *(const float4*)(Wsrc + (n0 + row) * DDIM + k0 + seg * 8);
        float4 g1 = *(const float4*)(Wsrc + (n0 + row) * DDIM + k0 + seg * 8 + 4);
        f16x8 bv;
        bv[0] = (f16)g0.x; bv[1] = (f16)g0.y; bv[2] = (f16)g0.z; bv[3] = (f16)g0.w;
        bv[4] = (f16)g1.x; bv[5] = (f16)g1.y; bv[6] = (f16)g1.z; bv[7] = (f16)g1.w;
        *(f16x8*)(Bs + row * 40 + seg * 8) = bv;
        __syncthreads();
        f16x8 afr[2], bfr[2];
#pragma unroll
        for (int t = 0; t < 2; ++t)
            afr[t] = *(const f16x8*)(As + (wm * 32 + t * 16 + m16) * 40 + quad * 8);
#pragma unroll
        for (int t = 0; t < 2; ++t)
            bfr[t] = *(const f16x8*)(Bs + (wn * 32 + t * 16 + m16) * 40 + quad * 8);
#pragma unroll
        for (int a = 0; a < 2; ++a)
#pragma unroll
            for (int c = 0; c < 2; ++c)
                acc[a][c] = __builtin_amdgcn_mfma_f32_16x16x32_f16(afr[a], bfr[c], acc[a][c], 0, 0, 0);
        __syncthreads();
    }
#pragma unroll
    for (int c = 0; c < 2; ++c) {
        int col = n0 + wn * 32 + c * 16 + m16;
        float bv = bias[col];
#pragma unroll
        for (int a = 0; a < 2; ++a) {
            int rbase = m0 + wm * 32 + a * 16 + quad * 4;
#pragma unroll
            for (int i = 0; i < 4; ++i)
                proj[(size_t)(rbase + i) * DDIM + col] = (f16)(acc[a][c][i] + bv);
        }
    }
}

// ---------------------------------------------------------------------------
// Kernel 2: A/Bp transposed. ABt[h][m], m<1024: A = l_proj @ W1a^T ;
// m>=1024: Bp = p_proj @ W1b^T.  fp32, [128][2048] layout for float4 acc-init.
// ---------------------------------------------------------------------------
__global__ __launch_bounds__(256) void prep_ab(
    const f16* __restrict__ proj, const float* __restrict__ W1,
    float* __restrict__ ABt) {
    __shared__ __align__(16) char sm[2 * 64 * 80];
    f16* As = (f16*)sm;
    f16* Bs = (f16*)(sm + 64 * 80);
    int tid = threadIdx.x;
    int m0 = blockIdx.x * 64, n0 = blockIdx.y * 64;
    bool isP = (m0 >= 1024);
    int koff = isP ? 256 : 0;
    int row = tid >> 2, seg = tid & 3;
    int w = tid >> 6, lane = tid & 63;
    int m16 = lane & 15, quad = lane >> 4;
    int wm = w & 1, wn = w >> 1;
    floatx4 acc[2][2];
#pragma unroll
    for (int a = 0; a < 2; ++a)
#pragma unroll
        for (int c = 0; c < 2; ++c) acc[a][c] = (floatx4)0.f;
    for (int k0 = 0; k0 < DDIM; k0 += 32) {
        f16x8 av = *(const f16x8*)(proj + (size_t)(m0 + row) * DDIM + k0 + seg * 8);
        *(f16x8*)(As + row * 40 + seg * 8) = av;
        float4 g0 = *(const float4*)(W1 + (size_t)(n0 + row) * 1024 + koff + k0 + seg * 8);
        float4 g1 = *(const float4*)(W1 + (size_t)(n0 + row) * 1024 + koff + k0 + seg * 8 + 4);
        f16x8 bv;
        bv[0] = (f16)g0.x; bv[1] = (f16)g0.y; bv[2] = (f16)g0.z; bv[3] = (f16)g0.w;
        bv[4] = (f16)g1.x; bv[5] = (f16)g1.y; bv[6] = (f16)g1.z; bv[7] = (f16)g1.w;
        *(f16x8*)(Bs + row * 40 + seg * 8) = bv;
        __syncthreads();
        f16x8 afr[2], bfr[2];
#pragma unroll
        for (int t = 0; t < 2; ++t)
            afr[t] = *(const f16x8*)(As + (wm * 32 + t * 16 + m16) * 40 + quad * 8);
#pragma unroll
        for (int t = 0; t < 2; ++t)
            bfr[t] = *(const f16x8*)(Bs + (wn * 32 + t * 16 + m16) * 40 + quad * 8);
#pragma unroll
        for (int a = 0; a < 2; ++a)
#pragma unroll
            for (int c = 0; c < 2; ++c)
                acc[a][c] = __builtin_amdgcn_mfma_f32_16x16x32_f16(afr[a], bfr[c], acc[a][c], 0, 0, 0);
        __syncthreads();
    }
#pragma unroll
    for (int c = 0; c < 2; ++c) {
        int col = n0 + wn * 32 + c * 16 + m16;
#pragma unroll
        for (int a = 0; a < 2; ++a) {
            int rbase = m0 + wm * 32 + a * 16 + quad * 4;
#pragma unroll
            for (int i = 0; i < 4; ++i)
                ABt[(size_t)col * 2048 + rbase + i] = acc[a][c][i];
        }
    }
}

// ---------------------------------------------------------------------------
// Kernel 3: main pair kernel. One block per (b,l). 512 threads = 8 waves.
// Fragment-ordered LDS (conflict-free), double-buffered X slots, packed f16
// X-gen, one barrier per K-step.
// ---------------------------------------------------------------------------
// LDS map (bytes):
//   [0, 32768)        W2 fragments (persistent through GEMM2)
//   [32768, 131072)   two X slots of 49152: {XA 16K | XB 16K | WC 8K | WD 8K}
//                     h1 fragments (65536) overlay this region in phase 2
//   [131072, 132096)  plog (256 f32)
#define SLOT 49152
#define XA_O 0
#define XB_O 16384
#define WC_O 32768
#define WD_O 40960
#define SM_X 32768
#define SM_H1 32768
#define SM_PLOG 131072
#define SM_TOTAL 132096

__global__ __launch_bounds__(512, 2) void pair_main(
    const f16* __restrict__ proj, const float* __restrict__ ABt,
    const f16* __restrict__ w1cd, const f16* __restrict__ w2b,
    const float* __restrict__ b1, const float* __restrict__ b2,
    const float* __restrict__ W3, const float* __restrict__ b3,
    const int* __restrict__ l_pad, const int* __restrict__ p_pad,
    float* __restrict__ out) {
    __shared__ __align__(16) char sm[SM_TOTAL];
    int tid = threadIdx.x;
    int l = blockIdx.x, b = blockIdx.y;
    float* outPL = out + 4;
    float* outPR = out + 4 + BB * LLL * LPP;
    size_t rowbase = ((size_t)(b * LLL + l)) * LPP;

    if (l_pad[b * LLL + l] != 0) {
        float pr = sigmoid_f(-20.f);
        if (tid < LPP) {
            outPL[rowbase + tid] = -20.f;
            outPR[rowbase + tid] = pr;
        }
        return;
    }

    float* plog = (float*)(sm + SM_PLOG);
    char* smX = sm + SM_X;
    char* w2s = sm;
    char* h1s = sm + SM_H1;

    int lane = tid & 63, w = tid >> 6;
    int m16 = lane & 15, quad = lane >> 4;
    int wp = w & 3, wh = w >> 2;
    int p0 = wp * 64, h0 = wh * 64;

    // W2 -> LDS fragment order: chunk c=(gtile,ks,quad,n) at byte c*16
#pragma unroll
    for (int r = 0; r < 4; ++r) {
        int c = tid + 512 * r;
        int gt = c >> 8, ks = (c >> 6) & 3, q2 = (c >> 4) & 3, n = c & 15;
        f16x8 v = *(const f16x8*)(w2b + (gt * 16 + n) * HH + ks * 32 + q2 * 8);
        *(f16x8*)(w2s + c * 16) = v;
    }
    if (tid < 256) plog[tid] = 0.f;

    // generator indices: thread (prow = tid>>2, kg = tid&3) handles rows prow, prow+128
    int kg = tid & 3, prow = tid >> 2;
    const f16* Lrow = proj + (size_t)(b * LLL + l) * DDIM + kg * 8;
    const f16* Prow0 = proj + (size_t)(1024 + b * LPP + prow) * DDIM + kg * 8;
    const f16* Prow1 = Prow0 + 128 * DDIM;
    const f16* Wrow = w1cd + (size_t)prow * 512 + kg * 8;
    int xdst = (prow >> 4) * 1024 + kg * 256 + (prow & 15) * 16;

    f16x8 lreg[8];
#pragma unroll
    for (int d = 0; d < 8; ++d) lreg[d] = *(const f16x8*)(Lrow + d * 32);

    f16x8 Pv0 = *(const f16x8*)(Prow0);
    f16x8 Pv1 = *(const f16x8*)(Prow1);
    f16x8 Wcv = *(const f16x8*)(Wrow);
    f16x8 Wdv = *(const f16x8*)(Wrow + 256);

    // accumulator init: A[l,h] + b1[h] + Bp[p,h] (float4 via transposed ABt)
    floatx4 acc[4][4];
    {
        int ml = b * LLL + l;
        float av4[4];
#pragma unroll
        for (int th = 0; th < 4; ++th) {
            int chh = h0 + th * 16 + m16;
            av4[th] = ABt[(size_t)chh * 2048 + ml] + b1[chh];
        }
#pragma unroll
        for (int tp = 0; tp < 4; ++tp) {
            int rp = p0 + tp * 16 + quad * 4;
#pragma unroll
            for (int th = 0; th < 4; ++th) {
                int chh = h0 + th * 16 + m16;
                floatx4 bp4 = *(const floatx4*)(ABt + (size_t)chh * 2048 + 1024 + b * LPP + rp);
                floatx4 a;
#pragma unroll
                for (int i = 0; i < 4; ++i) a[i] = bp4[i] + av4[th];
                acc[tp][th] = a;
            }
        }
    }

    // generate ds=0 into slot0; prefetch ds=1
    {
        char* nb = smX;
        *(f16x8*)(nb + WC_O + xdst) = Wcv;
        *(f16x8*)(nb + WD_O + xdst) = Wdv;
        f16x8 l8 = lreg[0];
        f16x8 pr = l8 * Pv0, ad = habs8(l8 - Pv0);
        *(f16x8*)(nb + XA_O + xdst) = pr;
        *(f16x8*)(nb + XB_O + xdst) = ad;
        pr = l8 * Pv1; ad = habs8(l8 - Pv1);
        *(f16x8*)(nb + XA_O + xdst + 8192) = pr;
        *(f16x8*)(nb + XB_O + xdst + 8192) = ad;
        Pv0 = *(const f16x8*)(Prow0 + 32);
        Pv1 = *(const f16x8*)(Prow1 + 32);
        Wcv = *(const f16x8*)(Wrow + 32);
        Wdv = *(const f16x8*)(Wrow + 256 + 32);
    }
    __syncthreads();

    int aoff[4], boff[4];
#pragma unroll
    for (int t = 0; t < 4; ++t) {
        aoff[t] = (wp * 4 + t) * 1024 + quad * 256 + m16 * 16;
        boff[t] = (wh * 4 + t) * 1024 + quad * 256 + m16 * 16;
    }

    // GEMM1 K-loop: 8 d-steps of 32; one barrier each; gen(ds+1) overlaps MFMA(ds)
#pragma unroll
    for (int ds = 0; ds < 8; ++ds) {
        char* cb = smX + (ds & 1) * SLOT;
        char* nb = smX + ((ds + 1) & 1) * SLOT;
        if (ds < 7) {
            *(f16x8*)(nb + WC_O + xdst) = Wcv;
            *(f16x8*)(nb + WD_O + xdst) = Wdv;
            f16x8 l8 = lreg[ds + 1];
            f16x8 pr = l8 * Pv0, ad = habs8(l8 - Pv0);
            *(f16x8*)(nb + XA_O + xdst) = pr;
            *(f16x8*)(nb + XB_O + xdst) = ad;
            pr = l8 * Pv1; ad = habs8(l8 - Pv1);
            *(f16x8*)(nb + XA_O + xdst + 8192) = pr;
            *(f16x8*)(nb + XB_O + xdst + 8192) = ad;
            if (ds < 6) {
                Pv0 = *(const f16x8*)(Prow0 + (ds + 2) * 32);
                Pv1 = *(const f16x8*)(Prow1 + (ds + 2) * 32);
                Wcv = *(const f16x8*)(Wrow + (ds + 2) * 32);
                Wdv = *(const f16x8*)(Wrow + 256 + (ds + 2) * 32);
            }
        }
        f16x8 a1[4], a2[4], bc4[4], bd4[4];
#pragma unroll
        for (int t = 0; t < 4; ++t) {
            a1[t] = *(const f16x8*)(cb + XA_O + aoff[t]);
            a2[t] = *(const f16x8*)(cb + XB_O + aoff[t]);
            bc4[t] = *(const f16x8*)(cb + WC_O + boff[t]);
            bd4[t] = *(const f16x8*)(cb + WD_O + boff[t]);
        }
#pragma unroll
        for (int tp = 0; tp < 4; ++tp)
#pragma unroll
            for (int th = 0; th < 4; ++th) {
                acc[tp][th] = __builtin_amdgcn_mfma_f32_16x16x32_f16(a1[tp], bc4[th], acc[tp][th], 0, 0, 0);
                acc[tp][th] = __builtin_amdgcn_mfma_f32_16x16x32_f16(a2[tp], bd4[th], acc[tp][th], 0, 0, 0);
            }
        __syncthreads();
    }

    // epilogue 1: GELU -> h1 fragments (overlay X slots; last barrier protects)
    int hoff[4];
#pragma unroll
    for (int th = 0; th < 4; ++th) {
        int h = h0 + th * 16 + m16;
        hoff[th] = (h >> 5) * 1024 + ((h >> 3) & 3) * 256 + (h & 7) * 2;
    }
#pragma unroll
    for (int tp = 0; tp < 4; ++tp) {
        int ptb = (wp * 4 + tp) * 4096;
#pragma unroll
        for (int th = 0; th < 4; ++th) {
#pragma unroll
            for (int i = 0; i < 4; ++i)
                *(f16*)(h1s + ptb + hoff[th] + (quad * 4 + i) * 16) = (f16)gelu_f(acc[tp][th][i]);
        }
    }
    __syncthreads();

    // GEMM2: 256p x 128g, K=128, fragment-ordered reads
    float b2v[4], w3v[4];
#pragma unroll
    for (int th = 0; th < 4; ++th) {
        int cg = h0 + th * 16 + m16;
        b2v[th] = b2[cg];
        w3v[th] = W3[cg];
    }
    floatx4 acc2[4][4];
#pragma unroll
    for (int tp = 0; tp < 4; ++tp)
#pragma unroll
        for (int th = 0; th < 4; ++th) {
            floatx4 a;
            a[0] = a[1] = a[2] = a[3] = b2v[th];
            acc2[tp][th] = a;
        }
#pragma unroll
    for (int ks = 0; ks < 4; ++ks) {
        f16x8 af[4], bfm[4];
#pragma unroll
        for (int tp = 0; tp < 4; ++tp)
            af[tp] = *(const f16x8*)(h1s + (wp * 4 + tp) * 4096 + ks * 1024 + quad * 256 + m16 * 16);
#pragma unroll
        for (int th = 0; th < 4; ++th)
            bfm[th] = *(const f16x8*)(w2s + (wh * 4 + th) * 4096 + ks * 1024 + quad * 256 + m16 * 16);
#pragma unroll
        for (int tp = 0; tp < 4; ++tp)
#pragma unroll
            for (int th = 0; th < 4; ++th)
                acc2[tp][th] = __builtin_amdgcn_mfma_f32_16x16x32_f16(af[tp], bfm[th], acc2[tp][th], 0, 0, 0);
    }

    // epilogue 2: GELU, partial W3-dot, cross-lane reduce, accumulate to plog
    float part[16];
#pragma unroll
    for (int j = 0; j < 16; ++j) part[j] = 0.f;
#pragma unroll
    for (int tp = 0; tp < 4; ++tp)
#pragma unroll
        for (int th = 0; th < 4; ++th)
#pragma unroll
            for (int i = 0; i < 4; ++i)
                part[tp * 4 + i] += w3v[th] * gelu_f(acc2[tp][th][i]);
#pragma unroll
    for (int mask = 1; mask <= 8; mask <<= 1)
#pragma unroll
        for (int j = 0; j < 16; ++j) part[j] += __shfl_xor(part[j], mask, 64);
    if (m16 == 0) {
#pragma unroll
        for (int tp = 0; tp < 4; ++tp)
#pragma unroll
            for (int i = 0; i < 4; ++i)
                atomicAdd(&plog[p0 + tp * 16 + quad * 4 + i], part[tp * 4 + i]);
    }
    __syncthreads();

    if (tid < LPP) {
        int p = tid;
        float pl = plog[p] + b3[0];
        if (__builtin_isnan(pl)) pl = 0.f;
        else if (__builtin_isinf(pl)) pl = pl > 0.f ? 20.f : -20.f;
        if (p_pad[b * LPP + p] != 0) pl = -20.f;
        outPL[rowbase + p] = pl;
        outPR[rowbase + p] = sigmoid_f(pl);
    }
}

// ---------------------------------------------------------------------------
// Kernel 4: exact top-100 + softmax pool per batch. 1 block per b, 1024 thr.
// Radix select; pass 0 uses per-wave histogram replicas (conflict reduction).
// ---------------------------------------------------------------------------
__device__ __forceinline__ unsigned okey(float f) {
    unsigned u = __float_as_uint(f);
    return (u & 0x80000000u) ? ~u : (u | 0x80000000u);
}

__global__ __launch_bounds__(1024) void topk_k(const float* __restrict__ pl,
                                               float* __restrict__ out) {
    __shared__ int hist[16 * 256];
    __shared__ float redf[32];
    __shared__ unsigned bc_pref;
    __shared__ int bc_rem;
    __shared__ float bc_vmax;
    int b = blockIdx.x, tid = threadIdx.x;
    int wv = tid >> 6, lane = tid & 63;
    const float* src = pl + (size_t)b * 65536;
    float v[64];
#pragma unroll
    for (int j = 0; j < 16; ++j) {
        float4 t = ((const float4*)src)[tid + j * 1024];
        v[j * 4 + 0] = t.x; v[j * 4 + 1] = t.y; v[j * 4 + 2] = t.z; v[j * 4 + 3] = t.w;
    }
    float mx = v[0];
#pragma unroll
    for (int j = 1; j < 64; ++j) mx = fmaxf(mx, v[j]);
    for (int off = 32; off > 0; off >>= 1) mx = fmaxf(mx, __shfl_xor(mx, off, 64));
    if (lane == 0) redf[wv] = mx;
    // pass 0: per-wave 256-bin histograms
#pragma unroll
    for (int r = 0; r < 4; ++r) hist[tid + r * 1024] = 0;
    __syncthreads();
    if (tid == 0) {
        float m = redf[0];
        for (int i = 1; i < 16; ++i) m = fmaxf(m, redf[i]);
        bc_vmax = m;
    }
    {
        int rep = wv * 256;
#pragma unroll
        for (int j = 0; j < 64; ++j)
            atomicAdd(&hist[(okey(v[j]) >> 24) + rep], 1);
    }
    __syncthreads();
    if (tid < 256) {
        int s = 0;
#pragma unroll
        for (int ww = 0; ww < 16; ++ww) s += hist[ww * 256 + tid];
        hist[tid] = s;
    }
    __syncthreads();
    unsigned pref = 0;
    int rem = 100;
    if (tid == 0) {
        int cum = 0, chosen = 0, above = 0;
        for (int bin = 255; bin >= 0; --bin) {
            int c = hist[bin];
            if (cum + c >= rem) { chosen = bin; above = cum; break; }
            cum += c;
        }
        bc_pref = (unsigned)chosen;
        bc_rem = rem - above;
    }
    __syncthreads();
    pref = bc_pref;
    rem = bc_rem;
    // passes 1..3: few candidates, 2 replicas
    for (int pass = 1; pass < 4; ++pass) {
        __syncthreads();
        if (tid < 512) hist[tid] = 0;
        __syncthreads();
        int sh = 24 - 8 * pass;
        int rep = (wv & 1) * 256;
#pragma unroll
        for (int j = 0; j < 64; ++j) {
            unsigned u = okey(v[j]);
            if ((u >> (sh + 8)) == pref) atomicAdd(&hist[((u >> sh) & 255) + rep], 1);
        }
        __syncthreads();
        if (tid == 0) {
            int cum = 0, chosen = 0, above = 0;
            for (int bin = 255; bin >= 0; --bin) {
                int c = hist[bin] + hist[bin + 256];
                if (cum + c >= rem) { chosen = bin; above = cum; break; }
                cum += c;
            }
            bc_pref = (pref << 8) | (unsigned)chosen;
            bc_rem = rem - above;
        }
        __syncthreads();
        pref = bc_pref;
        rem = bc_rem;
    }
    float vmax = bc_vmax;
    float s1 = 0.f, s2 = 0.f;
#pragma unroll
    for (int j = 0; j < 64; ++j) {
        if (okey(v[j]) > pref) {
            float e = __expf(v[j] - vmax);
            s1 += e;
            s2 += e * v[j];
        }
    }
    for (int off = 32; off > 0; off >>= 1) {
        s1 += __shfl_xor(s1, off, 64);
        s2 += __shfl_xor(s2, off, 64);
    }
    if (lane == 0) { redf[wv] = s1; redf[16 + wv] = s2; }
    __syncthreads();
    if (tid == 0) {
        float t1 = 0.f, t2 = 0.f;
        for (int i = 0; i < 16; ++i) { t1 += redf[i]; t2 += redf[16 + i]; }
        unsigned bits = (pref & 0x80000000u) ? (pref & 0x7fffffffu) : ~pref;
        float vT = __uint_as_float(bits);
        float e = __expf(vT - vmax);
        t1 += (float)rem * e;
        t2 += (float)rem * e * vT;
        out[b] = t2 / t1;
    }
}

// ---------------------------------------------------------------------------
extern "C" void kernel_launch(void* const* d_in, const int* in_sizes, int n_in,
                              void* d_out, int out_size, void* d_ws, size_t ws_size,
                              hipStream_t stream) {
    const float* l_tok = (const float*)d_in[0];
    const float* p_tok = (const float*)d_in[1];
    const int* l_pad = (const int*)d_in[2];
    const int* p_pad = (const int*)d_in[3];
    const float* Wl = (const float*)d_in[4];
    const float* bl = (const float*)d_in[5];
    const float* Wp = (const float*)d_in[6];
    const float* bp = (const float*)d_in[7];
    const float* W1 = (const float*)d_in[8];
    const float* b1 = (const float*)d_in[9];
    const float* W2 = (const float*)d_in[10];
    const float* b2 = (const float*)d_in[11];
    const float* W3 = (const float*)d_in[12];
    const float* b3 = (const float*)d_in[13];
    float* out = (float*)d_out;

    char* ws = (char*)d_ws;
    f16* proj = (f16*)ws;                                       // 2048*256 f16 = 1 MiB
    float* ABt = (float*)(ws + (size_t)2048 * 256 * 2);         // 128*2048 f32 = 1 MiB
    f16* w1cd = (f16*)(ws + (size_t)2048 * 256 * 2 + (size_t)128 * 2048 * 4);  // 128*512 f16
    f16* w2b = (f16*)((char*)w1cd + (size_t)128 * 512 * 2);     // 128*128 f16

    cvt_w<<<320, 256, 0, stream>>>(W1, W2, w1cd, w2b);
    prep_proj<<<dim3(32, 4), 256, 0, stream>>>(l_tok, p_tok, Wl, Wp, bl, bp, proj);
    prep_ab<<<dim3(32, 2), 256, 0, stream>>>(proj, W1, ABt);
    pair_main<<<dim3(LLL, BB), 512, 0, stream>>>(proj, ABt, w1cd, w2b, b1, b2, W3, b3,
                                                 l_pad, p_pad, out);
    topk_k<<<BB, 1024, 0, stream>>>(out + 4, out);
}

// Round 3
// 249.282 us; speedup vs baseline: 1.1449x; 1.1449x over previous
//
#include <hip/hip_runtime.h>

// Problem constants
#define BB 4
#define LLL 256
#define LPP 256
#define DDIM 256
#define HH 128

typedef _Float16 f16;
typedef f16 f16x8 __attribute__((ext_vector_type(8)));
typedef float floatx4 __attribute__((ext_vector_type(4)));

__device__ __forceinline__ float gelu_f(float x) {
    // x * sigmoid(1.702x): |err| vs erf-GELU < ~0.02, tolerance is 0.4 absolute.
    return x / (1.f + __expf(-1.702f * x));
}
__device__ __forceinline__ float sigmoid_f(float x) {
    return 1.f / (1.f + __expf(-x));
}
__device__ __forceinline__ f16x8 habs8(f16x8 v) {
    uint4 u = __builtin_bit_cast(uint4, v);
    u.x &= 0x7fff7fffu; u.y &= 0x7fff7fffu; u.z &= 0x7fff7fffu; u.w &= 0x7fff7fffu;
    return __builtin_bit_cast(f16x8, u);
}
__device__ __forceinline__ unsigned okey(float f) {
    unsigned u = __float_as_uint(f);
    return (u & 0x80000000u) ? ~u : (u | 0x80000000u);
}

// ---------------------------------------------------------------------------
// Kernel 0: build fragment-ordered f16 copies of W1c|W1d and (pi-permuted) W2.
// w1g chunk c (16B): c = ((ds*2+cd)*8+th)*64 + quad*16 + m16
//   holds W1[h=th*16+m16][512 + cd*256 + ds*32 + quad*8 + j], j=0..7
// w2g chunk c: c = (ks*8+tg)*64 + quad*16 + m16
//   holds W2[g=tg*16+m16][h = j*16 + ks*4 + quad]   (pi: k' = (h&15)*8 + (h>>4))
// ---------------------------------------------------------------------------
__global__ void cvt_w(const float* __restrict__ W1, const float* __restrict__ W2,
                      f16* __restrict__ w1g, f16* __restrict__ w2g) {
    int idx = blockIdx.x * 256 + threadIdx.x;
    if (idx < 8192) {
        int m16 = idx & 15, quad = (idx >> 4) & 3, th = (idx >> 6) & 7;
        int cd = (idx >> 9) & 1, ds = idx >> 10;
        int h = th * 16 + m16;
        const float* src = W1 + (size_t)h * 1024 + 512 + cd * 256 + ds * 32 + quad * 8;
        f16x8 v;
#pragma unroll
        for (int j = 0; j < 8; ++j) v[j] = (f16)src[j];
        *(f16x8*)(w1g + (size_t)idx * 8) = v;
    } else if (idx < 8192 + 2048) {
        int c = idx - 8192;
        int m16 = c & 15, quad = (c >> 4) & 3, tg = (c >> 6) & 7, ks = c >> 9;
        int g = tg * 16 + m16;
        f16x8 v;
#pragma unroll
        for (int j = 0; j < 8; ++j) v[j] = (f16)W2[g * HH + j * 16 + ks * 4 + quad];
        *(f16x8*)(w2g + (size_t)c * 8) = v;
    }
}

// ---------------------------------------------------------------------------
// Kernel 1: projections. proj[m][e], m in [0,1024): l rows, [1024,2048): p rows
// ---------------------------------------------------------------------------
__global__ __launch_bounds__(256) void prep_proj(
    const float* __restrict__ l_tok, const float* __restrict__ p_tok,
    const float* __restrict__ Wl, const float* __restrict__ Wp,
    const float* __restrict__ bl, const float* __restrict__ bp,
    f16* __restrict__ proj) {
    __shared__ __align__(16) char sm[2 * 64 * 80];
    f16* As = (f16*)sm;
    f16* Bs = (f16*)(sm + 64 * 80);
    int tid = threadIdx.x;
    int m0 = blockIdx.x * 64, n0 = blockIdx.y * 64;
    bool isP = (m0 >= 1024);
    const float* Asrc = isP ? (p_tok + (size_t)(m0 - 1024) * DDIM) : (l_tok + (size_t)m0 * DDIM);
    const float* Wsrc = isP ? Wp : Wl;
    const float* bias = isP ? bp : bl;
    int row = tid >> 2, seg = tid & 3;
    int w = tid >> 6, lane = tid & 63;
    int m16 = lane & 15, quad = lane >> 4;
    int wm = w & 1, wn = w >> 1;
    floatx4 acc[2][2];
#pragma unroll
    for (int a = 0; a < 2; ++a)
#pragma unroll
        for (int c = 0; c < 2; ++c) acc[a][c] = (floatx4)0.f;
    for (int k0 = 0; k0 < DDIM; k0 += 32) {
        float4 f0 = *(const float4*)(Asrc + row * DDIM + k0 + seg * 8);
        float4 f1 = *(const float4*)(Asrc + row * DDIM + k0 + seg * 8 + 4);
        f16x8 av;
        av[0] = (f16)f0.x; av[1] = (f16)f0.y; av[2] = (f16)f0.z; av[3] = (f16)f0.w;
        av[4] = (f16)f1.x; av[5] = (f16)f1.y; av[6] = (f16)f1.z; av[7] = (f16)f1.w;
        *(f16x8*)(As + row * 40 + seg * 8) = av;
        float4 g0 = *(const float4*)(Wsrc + (n0 + row) * DDIM + k0 + seg * 8);
        float4 g1 = *(const float4*)(Wsrc + (n0 + row) * DDIM + k0 + seg * 8 + 4);
        f16x8 bv;
        bv[0] = (f16)g0.x; bv[1] = (f16)g0.y; bv[2] = (f16)g0.z; bv[3] = (f16)g0.w;
        bv[4] = (f16)g1.x; bv[5] = (f16)g1.y; bv[6] = (f16)g1.z; bv[7] = (f16)g1.w;
        *(f16x8*)(Bs + row * 40 + seg * 8) = bv;
        __syncthreads();
        f16x8 afr[2], bfr[2];
#pragma unroll
        for (int t = 0; t < 2; ++t)
            afr[t] = *(const f16x8*)(As + (wm * 32 + t * 16 + m16) * 40 + quad * 8);
#pragma unroll
        for (int t = 0; t < 2; ++t)
            bfr[t] = *(const f16x8*)(Bs + (wn * 32 + t * 16 + m16) * 40 + quad * 8);
#pragma unroll
        for (int a = 0; a < 2; ++a)
#pragma unroll
            for (int c = 0; c < 2; ++c)
                acc[a][c] = __builtin_amdgcn_mfma_f32_16x16x32_f16(afr[a], bfr[c], acc[a][c], 0, 0, 0);
        __syncthreads();
    }
#pragma unroll
    for (int c = 0; c < 2; ++c) {
        int col = n0 + wn * 32 + c * 16 + m16;
        float bv = bias[col];
#pragma unroll
        for (int a = 0; a < 2; ++a) {
            int rbase = m0 + wm * 32 + a * 16 + quad * 4;
#pragma unroll
            for (int i = 0; i < 4; ++i)
                proj[(size_t)(rbase + i) * DDIM + col] = (f16)(acc[a][c][i] + bv);
        }
    }
}

// ---------------------------------------------------------------------------
// Kernel 2: A/Bp transposed. ABt[h][m] (fp32 [128][2048]).
// m<1024: A = l_proj @ W1a^T ; m>=1024: Bp = p_proj @ W1b^T
// ---------------------------------------------------------------------------
__global__ __launch_bounds__(256) void prep_ab(
    const f16* __restrict__ proj, const float* __restrict__ W1,
    float* __restrict__ ABt) {
    __shared__ __align__(16) char sm[2 * 64 * 80];
    f16* As = (f16*)sm;
    f16* Bs = (f16*)(sm + 64 * 80);
    int tid = threadIdx.x;
    int m0 = blockIdx.x * 64, n0 = blockIdx.y * 64;
    bool isP = (m0 >= 1024);
    int koff = isP ? 256 : 0;
    int row = tid >> 2, seg = tid & 3;
    int w = tid >> 6, lane = tid & 63;
    int m16 = lane & 15, quad = lane >> 4;
    int wm = w & 1, wn = w >> 1;
    floatx4 acc[2][2];
#pragma unroll
    for (int a = 0; a < 2; ++a)
#pragma unroll
        for (int c = 0; c < 2; ++c) acc[a][c] = (floatx4)0.f;
    for (int k0 = 0; k0 < DDIM; k0 += 32) {
        f16x8 av = *(const f16x8*)(proj + (size_t)(m0 + row) * DDIM + k0 + seg * 8);
        *(f16x8*)(As + row * 40 + seg * 8) = av;
        float4 g0 = *(const float4*)(W1 + (size_t)(n0 + row) * 1024 + koff + k0 + seg * 8);
        float4 g1 = *(const float4*)(W1 + (size_t)(n0 + row) * 1024 + koff + k0 + seg * 8 + 4);
        f16x8 bv;
        bv[0] = (f16)g0.x; bv[1] = (f16)g0.y; bv[2] = (f16)g0.z; bv[3] = (f16)g0.w;
        bv[4] = (f16)g1.x; bv[5] = (f16)g1.y; bv[6] = (f16)g1.z; bv[7] = (f16)g1.w;
        *(f16x8*)(Bs + row * 40 + seg * 8) = bv;
        __syncthreads();
        f16x8 afr[2], bfr[2];
#pragma unroll
        for (int t = 0; t < 2; ++t)
            afr[t] = *(const f16x8*)(As + (wm * 32 + t * 16 + m16) * 40 + quad * 8);
#pragma unroll
        for (int t = 0; t < 2; ++t)
            bfr[t] = *(const f16x8*)(Bs + (wn * 32 + t * 16 + m16) * 40 + quad * 8);
#pragma unroll
        for (int a = 0; a < 2; ++a)
#pragma unroll
            for (int c = 0; c < 2; ++c)
                acc[a][c] = __builtin_amdgcn_mfma_f32_16x16x32_f16(afr[a], bfr[c], acc[a][c], 0, 0, 0);
        __syncthreads();
    }
#pragma unroll
    for (int c = 0; c < 2; ++c) {
        int col = n0 + wn * 32 + c * 16 + m16;
#pragma unroll
        for (int a = 0; a < 2; ++a) {
            int rbase = m0 + wm * 32 + a * 16 + quad * 4;
#pragma unroll
            for (int i = 0; i < 4; ++i)
                ABt[(size_t)col * 2048 + rbase + i] = acc[a][c][i];
        }
    }
}

// ---------------------------------------------------------------------------
// Kernel 3: main pair kernel. One block per 2 l-rows, 512 threads = 8 waves.
// Wave w: l-half = w>>2, p-range = (w&3)*64. Wave owns 64p x 128h autonomously.
// GEMM1 K-loop is BARRIER-FREE: A-frags (l*p, |l-p|) generated in registers
// from global proj loads; B-frags (W1c/W1d) read from LDS (staged once,
// fragment-ordered). Only 2 barriers total (around the h1 LDS transpose).
// LDS: w1s 128 KB, overlaid by h1' (2 x 256 x 128 f16, pi-permuted h).
// ---------------------------------------------------------------------------
__global__ __launch_bounds__(512, 2) void pair_main(
    const f16* __restrict__ proj, const float* __restrict__ ABt,
    const f16* __restrict__ w1g, const f16* __restrict__ w2g,
    const float* __restrict__ b1, const float* __restrict__ b2,
    const float* __restrict__ W3, const float* __restrict__ b3,
    const int* __restrict__ l_pad, const int* __restrict__ p_pad,
    float* __restrict__ out) {
    __shared__ __align__(16) char sm[131072];
    int tid = threadIdx.x;
    int lane = tid & 63, w = tid >> 6;
    int m16 = lane & 15, quad = lane >> 4;
    int lhalf = w >> 2, wp = w & 3;
    int p0 = wp * 64;
    int b = blockIdx.y;
    int l = blockIdx.x * 2 + lhalf;
    int ml = b * LLL + l;
    bool padL = (l_pad[ml] != 0);
    float* outPL = out + 4;
    float* outPR = out + 4 + BB * LLL * LPP;
    size_t rowbase = (size_t)ml * LPP;

    // stage fragment-ordered W1c|W1d into LDS (linear 128 KB copy)
#pragma unroll
    for (int r = 0; r < 16; ++r) {
        int c = tid + r * 512;
        *(f16x8*)(sm + c * 16) = *(const f16x8*)(w1g + (size_t)c * 8);
    }

    // accumulator init: A[l,h] + b1[h] + Bp[p,h]
    floatx4 acc[4][8];
    if (!padL) {
        float av[8];
#pragma unroll
        for (int th = 0; th < 8; ++th) {
            int hh = th * 16 + m16;
            av[th] = ABt[(size_t)hh * 2048 + ml] + b1[hh];
        }
#pragma unroll
        for (int tp = 0; tp < 4; ++tp) {
            int rp = p0 + tp * 16 + quad * 4;
#pragma unroll
            for (int th = 0; th < 8; ++th) {
                int hh = th * 16 + m16;
                floatx4 bp4 = *(const floatx4*)(ABt + (size_t)hh * 2048 + 1024 + b * LPP + rp);
                floatx4 a;
#pragma unroll
                for (int i = 0; i < 4; ++i) a[i] = bp4[i] + av[th];
                acc[tp][th] = a;
            }
        }
    }
    __syncthreads();

    if (!padL) {
        const f16* Lr = proj + (size_t)ml * DDIM + quad * 8;
        const f16* Pr = proj + (size_t)(1024 + b * LPP) * DDIM + quad * 8;
        for (int ds = 0; ds < 8; ++ds) {
            f16x8 lv = *(const f16x8*)(Lr + ds * 32);
            f16x8 x1[4], x2[4];
#pragma unroll
            for (int tp = 0; tp < 4; ++tp) {
                f16x8 pv = *(const f16x8*)(Pr + (size_t)(p0 + tp * 16 + m16) * DDIM + ds * 32);
                x1[tp] = lv * pv;
                x2[tp] = habs8(lv - pv);
            }
            char* bbase = sm + ds * 16384 + quad * 256 + m16 * 16;
            f16x8 bfr[8];
#pragma unroll
            for (int th = 0; th < 8; ++th)
                bfr[th] = *(const f16x8*)(bbase + th * 1024);
#pragma unroll
            for (int tp = 0; tp < 4; ++tp)
#pragma unroll
                for (int th = 0; th < 8; ++th)
                    acc[tp][th] = __builtin_amdgcn_mfma_f32_16x16x32_f16(x1[tp], bfr[th], acc[tp][th], 0, 0, 0);
#pragma unroll
            for (int th = 0; th < 8; ++th)
                bfr[th] = *(const f16x8*)(bbase + 8192 + th * 1024);
#pragma unroll
            for (int tp = 0; tp < 4; ++tp)
#pragma unroll
                for (int th = 0; th < 8; ++th)
                    acc[tp][th] = __builtin_amdgcn_mfma_f32_16x16x32_f16(x2[tp], bfr[th], acc[tp][th], 0, 0, 0);
        }
    }
    __syncthreads();

    // h1' (pi-space) -> LDS overlay: lane's th-values are k'-contiguous => b128
    char* h1s = sm + lhalf * 65536;
    if (!padL) {
#pragma unroll
        for (int tp = 0; tp < 4; ++tp) {
#pragma unroll
            for (int i = 0; i < 4; ++i) {
                f16x8 hv;
#pragma unroll
                for (int th = 0; th < 8; ++th) hv[th] = (f16)gelu_f(acc[tp][th][i]);
                int p = p0 + tp * 16 + quad * 4 + i;
                *(f16x8*)(h1s + p * 256 + m16 * 16) = hv;
            }
        }
    }
    __syncthreads();

    if (!padL) {
        // GEMM2: wave's 64p x 128g, K'=128 (pi-permuted; W2 pre-permuted in w2g)
        float b2v[8], w3v[8];
#pragma unroll
        for (int tg = 0; tg < 8; ++tg) {
            int g = tg * 16 + m16;
            b2v[tg] = b2[g];
            w3v[tg] = W3[g];
        }
        floatx4 acc2[4][8];
#pragma unroll
        for (int tp = 0; tp < 4; ++tp)
#pragma unroll
            for (int tg = 0; tg < 8; ++tg) {
                floatx4 a;
                a[0] = a[1] = a[2] = a[3] = b2v[tg];
                acc2[tp][tg] = a;
            }
#pragma unroll
        for (int ks = 0; ks < 4; ++ks) {
            f16x8 af[4];
#pragma unroll
            for (int tp = 0; tp < 4; ++tp)
                af[tp] = *(const f16x8*)(h1s + (p0 + tp * 16 + m16) * 256 + ks * 64 + quad * 16);
            f16x8 bf2[8];
#pragma unroll
            for (int tg = 0; tg < 8; ++tg)
                bf2[tg] = *(const f16x8*)(w2g + (size_t)(((ks * 8 + tg) * 4 + quad) * 16 + m16) * 8);
#pragma unroll
            for (int tp = 0; tp < 4; ++tp)
#pragma unroll
                for (int tg = 0; tg < 8; ++tg)
                    acc2[tp][tg] = __builtin_amdgcn_mfma_f32_16x16x32_f16(af[tp], bf2[tg], acc2[tp][tg], 0, 0, 0);
        }

        // epilogue: gelu, W3 dot, reduce over m16, direct global write (no atomics:
        // each wave exclusively owns its 64-p range)
        float part[16];
#pragma unroll
        for (int j = 0; j < 16; ++j) part[j] = 0.f;
#pragma unroll
        for (int tp = 0; tp < 4; ++tp)
#pragma unroll
            for (int tg = 0; tg < 8; ++tg)
#pragma unroll
                for (int i = 0; i < 4; ++i)
                    part[tp * 4 + i] += w3v[tg] * gelu_f(acc2[tp][tg][i]);
#pragma unroll
        for (int mask = 1; mask <= 8; mask <<= 1)
#pragma unroll
            for (int j = 0; j < 16; ++j) part[j] += __shfl_xor(part[j], mask, 64);
        // writer mapping: lane (m16,quad) -> p = p0 + (m16>>2)*16 + quad*4 + (m16&3)
        int p = p0 + (m16 >> 2) * 16 + quad * 4 + (m16 & 3);
        float pl = part[m16] + b3[0];
        if (__builtin_isnan(pl)) pl = 0.f;
        else if (__builtin_isinf(pl)) pl = pl > 0.f ? 20.f : -20.f;
        if (p_pad[b * LPP + p] != 0) pl = -20.f;
        outPL[rowbase + p] = pl;
        outPR[rowbase + p] = sigmoid_f(pl);
    } else {
        int p = p0 + lane;
        outPL[rowbase + p] = -20.f;
        outPR[rowbase + p] = sigmoid_f(-20.f);
    }
}

// ---------------------------------------------------------------------------
// Kernel 4: exact top-100 + softmax pool per batch. 1 block per b, 1024 thr.
// Radix select re-streaming from L2 each pass (no register residency -> no
// scratch spills). The -20 mask spike is counted locally, one atomic per lane.
// ---------------------------------------------------------------------------
__global__ __launch_bounds__(1024) void topk_k(const float* __restrict__ pl,
                                               float* __restrict__ out) {
    __shared__ int hist[16 * 256];
    __shared__ float redf[32];
    __shared__ unsigned bc_pref;
    __shared__ int bc_rem;
    __shared__ float bc_vmax;
    int b = blockIdx.x, tid = threadIdx.x;
    int wv = tid >> 6, lane = tid & 63;
    const float4* src = (const float4*)(pl + (size_t)b * 65536);

#pragma unroll
    for (int r = 0; r < 4; ++r) hist[tid + r * 1024] = 0;
    __syncthreads();

    // pass 0: top-8-bit histogram (per-wave replicas) + max
    float mx = -1e30f;
    int c20 = 0;
    const unsigned bin20 = okey(-20.f) >> 24;
    {
        int rep = wv * 256;
        for (int j = 0; j < 16; ++j) {
            float4 t = src[tid + j * 1024];
#pragma unroll
            for (int c = 0; c < 4; ++c) {
                float v = (&t.x)[c];
                mx = fmaxf(mx, v);
                if (v == -20.f) c20++;
                else atomicAdd(&hist[rep + (okey(v) >> 24)], 1);
            }
        }
        atomicAdd(&hist[rep + bin20], c20);
    }
    for (int off = 32; off > 0; off >>= 1) mx = fmaxf(mx, __shfl_xor(mx, off, 64));
    if (lane == 0) redf[wv] = mx;
    __syncthreads();
    if (tid < 256) {
        int s = 0;
#pragma unroll
        for (int ww = 0; ww < 16; ++ww) s += hist[ww * 256 + tid];
        hist[tid] = s;
    }
    __syncthreads();
    if (tid == 0) {
        float m = redf[0];
        for (int i = 1; i < 16; ++i) m = fmaxf(m, redf[i]);
        bc_vmax = m;
        int cum = 0, chosen = 0, above = 0;
        for (int bin = 255; bin >= 0; --bin) {
            int c = hist[bin];
            if (cum + c >= 100) { chosen = bin; above = cum; break; }
            cum += c;
        }
        bc_pref = (unsigned)chosen;
        bc_rem = 100 - above;
    }
    __syncthreads();
    unsigned pref = bc_pref;
    int rem = bc_rem;

    for (int pass = 1; pass < 4; ++pass) {
        if (tid < 512) hist[tid] = 0;
        __syncthreads();
        int sh = 24 - 8 * pass;
        int rep = (wv & 1) * 256;
        for (int j = 0; j < 16; ++j) {
            float4 t = src[tid + j * 1024];
#pragma unroll
            for (int c = 0; c < 4; ++c) {
                unsigned u = okey((&t.x)[c]);
                if ((u >> (sh + 8)) == pref) atomicAdd(&hist[rep + ((u >> sh) & 255)], 1);
            }
        }
        __syncthreads();
        if (tid == 0) {
            int cum = 0, chosen = 0, above = 0;
            for (int bin = 255; bin >= 0; --bin) {
                int c = hist[bin] + hist[bin + 256];
                if (cum + c >= rem) { chosen = bin; above = cum; break; }
                cum += c;
            }
            bc_pref = (pref << 8) | (unsigned)chosen;
            bc_rem = rem - above;
        }
        __syncthreads();
        pref = bc_pref;
        rem = bc_rem;
        __syncthreads();
    }

    float vmax = bc_vmax;
    float s1 = 0.f, s2 = 0.f;
    for (int j = 0; j < 16; ++j) {
        float4 t = src[tid + j * 1024];
#pragma unroll
        for (int c = 0; c < 4; ++c) {
            float v = (&t.x)[c];
            if (okey(v) > pref) {
                float e = __expf(v - vmax);
                s1 += e;
                s2 += e * v;
            }
        }
    }
    for (int off = 32; off > 0; off >>= 1) {
        s1 += __shfl_xor(s1, off, 64);
        s2 += __shfl_xor(s2, off, 64);
    }
    if (lane == 0) { redf[wv] = s1; redf[16 + wv] = s2; }
    __syncthreads();
    if (tid == 0) {
        float t1 = 0.f, t2 = 0.f;
        for (int i = 0; i < 16; ++i) { t1 += redf[i]; t2 += redf[16 + i]; }
        unsigned bits = (pref & 0x80000000u) ? (pref & 0x7fffffffu) : ~pref;
        float vT = __uint_as_float(bits);
        float e = __expf(vT - vmax);
        t1 += (float)rem * e;
        t2 += (float)rem * e * vT;
        out[b] = t2 / t1;
    }
}

// ---------------------------------------------------------------------------
extern "C" void kernel_launch(void* const* d_in, const int* in_sizes, int n_in,
                              void* d_out, int out_size, void* d_ws, size_t ws_size,
                              hipStream_t stream) {
    const float* l_tok = (const float*)d_in[0];
    const float* p_tok = (const float*)d_in[1];
    const int* l_pad = (const int*)d_in[2];
    const int* p_pad = (const int*)d_in[3];
    const float* Wl = (const float*)d_in[4];
    const float* bl = (const float*)d_in[5];
    const float* Wp = (const float*)d_in[6];
    const float* bp = (const float*)d_in[7];
    const float* W1 = (const float*)d_in[8];
    const float* b1 = (const float*)d_in[9];
    const float* W2 = (const float*)d_in[10];
    const float* b2 = (const float*)d_in[11];
    const float* W3 = (const float*)d_in[12];
    const float* b3 = (const float*)d_in[13];
    float* out = (float*)d_out;

    char* ws = (char*)d_ws;
    f16* proj = (f16*)ws;                                       // 2048*256 f16 = 1 MiB
    float* ABt = (float*)(ws + (size_t)2048 * 256 * 2);         // 128*2048 f32 = 1 MiB
    f16* w1g = (f16*)(ws + (size_t)2048 * 256 * 2 + (size_t)128 * 2048 * 4);  // 128 KiB
    f16* w2g = (f16*)((char*)w1g + (size_t)8192 * 16);          // 32 KiB

    cvt_w<<<40, 256, 0, stream>>>(W1, W2, w1g, w2g);
    prep_proj<<<dim3(32, 4), 256, 0, stream>>>(l_tok, p_tok, Wl, Wp, bl, bp, proj);
    prep_ab<<<dim3(32, 2), 256, 0, stream>>>(proj, W1, ABt);
    pair_main<<<dim3(LLL / 2, BB), 512, 0, stream>>>(proj, ABt, w1g, w2g, b1, b2, W3, b3,
                                                     l_pad, p_pad, out);
    topk_k<<<BB, 1024, 0, stream>>>(out + 4, out);
}